// Round 12
// baseline (89.711 us; speedup 1.0000x reference)
//
#include <hip/hip_runtime.h>
#include <math.h>

typedef __attribute__((ext_vector_type(8))) short short8;
typedef __attribute__((ext_vector_type(4))) short short4v;
typedef __attribute__((ext_vector_type(4))) float f32x4;

namespace {

constexpr int kT = 12, kMS = 20, kE = 3;
constexpr int kSites = 64 * 325;                 // 20800
constexpr int kWaves = 8;
constexpr int kThreads = kWaves * 64;            // 512
constexpr int kNB = 340;                         // blocks per expert (1020 total ~ 4/CU)
constexpr int kStride = kNB * kWaves;            // 2720
constexpr int kIters = (kSites + kStride - 1) / kStride;  // 8

__device__ __forceinline__ void split1(float x, unsigned& hi, unsigned& lo) {
  unsigned u = __float_as_uint(x);
  hi = u >> 16;
  float r = x - __uint_as_float(u & 0xFFFF0000u);   // exact (Sterbenz)
  lo = __float_as_uint(r) >> 16;
}
__device__ __forceinline__ float btrunc(float x) {
  return __uint_as_float(__float_as_uint(x) & 0xFFFF0000u);
}
__device__ __forceinline__ unsigned pk_hi(float a, float b) {   // {bf(b):bf(a)}, a low
  return __builtin_amdgcn_perm(__float_as_uint(b), __float_as_uint(a), 0x07060302u);
}
__device__ __forceinline__ unsigned pk_rnd(float a, float b) {  // round-half-up bf16 pack
  return __builtin_amdgcn_perm(__float_as_uint(b) + 0x8000u,
                               __float_as_uint(a) + 0x8000u, 0x07060302u);
}

union S8 { short8 s; unsigned u[4]; };
union S4 { short4v s; unsigned u[2]; };

#define MFMA32(a, b, c) __builtin_amdgcn_mfma_f32_16x16x32_bf16((a), (b), (c), 0, 0, 0)
// gfx90a+ name on gfx950 (v_mfma_f32_16x16x16_bf16; A/B = 2 VGPR = 4 bf16).
// No __has_builtin guard — false in the HIP host pass (R10 lesson).
#define MFMA16(a, b, c) __builtin_amdgcn_mfma_f32_16x16x16bf16_1k((a), (b), (c), 0, 0, 0)

// Layouts (m89-verified K=32; classic K=16):
//   K=32 A: lane holds A[row=l&15][k=8g+j]; B: B[k=8g+j][col=l&15]
//   K=16 A: lane holds A[row=l&15][k=4g+j]; B: B[k=4g+j][col=l&15]
//   C/D (both): lane holds D[row=4g+r][col=l&15]
// => C-regs of X == A-frag(K=16) of X^T == B-frag(K=16) of X.  (zero-move chaining)
__global__ __launch_bounds__(kThreads, 4) void testam_mfma(
    const float* __restrict__ input, const float* __restrict__ h0,
    const float* __restrict__ h1, const float* __restrict__ h2,
    const float* __restrict__ memw, const float* __restrict__ iq,
    const float* __restrict__ hq, const float* __restrict__ kwt,
    const float* __restrict__ vw, float* __restrict__ out) {

  __shared__ __align__(16) unsigned short wlds[2][12][512];  // weight frags; hi plane read once
  __shared__ __align__(16) float Glds[32][4];                // G^T = (iq@memw^T)^T padded

  const int tid = threadIdx.x;
  const int e = blockIdx.x / kNB;
  const int b = blockIdx.x % kNB;
  const int l = tid & 63, wv = tid >> 6;
  const int g = l >> 4, c = l & 15;

  // ---- one-time staging: QKV weight frags (K=32) into LDS ----
  for (int idx = tid; idx < 768; idx += kThreads) {
    int ll = idx & 63, fi = idx >> 6;
    int mat = fi >> 2, x = (fi >> 1) & 1, y = fi & 1;
    int gg = ll >> 4, cc = ll & 15;
    const float* wp = ((mat == 0) ? hq : (mat == 1) ? kwt : vw) + e * 2048
                      + (y * 32 + gg * 8) * 32 + x * 16 + cc;
    short8 sh, sl;
    #pragma unroll
    for (int j = 0; j < 8; ++j) {
      unsigned h, lo; split1(wp[j * 32], h, lo);
      sh[j] = (short)h; sl[j] = (short)lo;
    }
    *(short8*)&wlds[0][fi][ll * 8] = sh;
    *(short8*)&wlds[1][fi][ll * 8] = sl;
  }
  for (int idx = tid; idx < 128; idx += kThreads) {
    int s = idx >> 2, d = idx & 3;
    float acc = 0.f;
    if (d < 3 && s < kMS) {
      for (int m = 0; m < 32; ++m) acc += iq[d * 32 + m] * memw[s * 32 + m];
    }
    Glds[s][d] = acc;
  }

  // ---- memw^T A-frags (K=16) straight into registers (once) ----
  S4 mwh[2][2], mwl[2][2];
  #pragma unroll
  for (int p = 0; p < 2; ++p)
    #pragma unroll
    for (int sch = 0; sch < 2; ++sch) {
      float v[4];
      #pragma unroll
      for (int j = 0; j < 4; ++j) {
        int s = 16 * sch + 4 * g + j;
        v[j] = (s < kMS) ? memw[s * 32 + 16 * p + c] : 0.f;
      }
      mwh[p][sch].u[0] = pk_hi(v[0], v[1]);
      mwh[p][sch].u[1] = pk_hi(v[2], v[3]);
      mwl[p][sch].u[0] = pk_hi(v[0] - btrunc(v[0]), v[1] - btrunc(v[1]));
      mwl[p][sch].u[1] = pk_hi(v[2] - btrunc(v[2]), v[3] - btrunc(v[3]));
    }
  __syncthreads();

  // ---- hoist hi-plane weight frags to registers (read once per sweep) ----
  // +48 VGPR; base was 52 -> ~100-110, under the 128 cap. Spill tripwire: WRITE_SIZE.
  short8 whiR[12];
  #pragma unroll
  for (int fi = 0; fi < 12; ++fi) whiR[fi] = *(const short8*)&wlds[0][fi][l * 8];

  const float* hbase = (e == 0) ? h0 : (e == 1) ? h1 : h2;
  const f32x4 fz = {0.f, 0.f, 0.f, 0.f};

  // lanes c>=12 read row 0 (finite); s>=12 slots meet exact-zero weights.
  const int crow = (c < kT) ? c : 0;

  float hcur[16], hnxt[16];
  float pcur[3], pnxt[3];

  auto load_site = [&](int s, float* hr, float* pr) {
    const int sc_ = (s < kSites) ? s : (kSites - 1);
    const float* p = hbase + (size_t)sc_ * 768 + crow * 64 + g * 8;
    #pragma unroll
    for (int k0i = 0; k0i < 2; ++k0i)
      #pragma unroll
      for (int j = 0; j < 8; ++j) hr[k0i * 8 + j] = p[k0i * 32 + j];
    const float* ip = input + (size_t)sc_ * 36 + crow * 3;
    pr[0] = ip[0]; pr[1] = ip[1]; pr[2] = ip[2];
  };

  int site = b * kWaves + wv;
  load_site(site, hcur, pcur);

  for (int it = 0; it < kIters; ++it) {
    const int nsite = site + kStride;
    load_site(nsite, hnxt, pnxt);

    if (site < kSites) {
      // ---- h A-frags (double as h^T B-frags), K=32 ----
      S8 ah[2], al[2];
      #pragma unroll
      for (int k0i = 0; k0i < 2; ++k0i)
        #pragma unroll
        for (int jj = 0; jj < 4; ++jj) {
          float a = hcur[k0i * 8 + 2 * jj], bb = hcur[k0i * 8 + 2 * jj + 1];
          ah[k0i].u[jj] = pk_hi(a, bb);
          al[k0i].u[jj] = pk_hi(a - btrunc(a), bb - btrunc(bb));
        }

      // ---- Q^T, K^T (swapped, A=W^T), V (direct); 3-term bf16x3 ----
      f32x4 cq[2] = {fz, fz}, ck[2] = {fz, fz}, cv[2] = {fz, fz};
      __builtin_amdgcn_s_setprio(1);
      #pragma unroll
      for (int p = 0; p < 2; ++p)
        #pragma unroll
        for (int k0i = 0; k0i < 2; ++k0i) {
          {
            const int fi = 0 + p * 2 + k0i;
            short8 wlo = *(const short8*)&wlds[1][fi][l * 8];
            cq[p] = MFMA32(whiR[fi], ah[k0i].s, cq[p]);
            cq[p] = MFMA32(whiR[fi], al[k0i].s, cq[p]);
            cq[p] = MFMA32(wlo, ah[k0i].s, cq[p]);
          }
          {
            const int fi = 4 + p * 2 + k0i;
            short8 wlo = *(const short8*)&wlds[1][fi][l * 8];
            ck[p] = MFMA32(whiR[fi], ah[k0i].s, ck[p]);
            ck[p] = MFMA32(whiR[fi], al[k0i].s, ck[p]);
            ck[p] = MFMA32(wlo, ah[k0i].s, ck[p]);
          }
          {
            const int fi = 8 + p * 2 + k0i;
            short8 wlo = *(const short8*)&wlds[1][fi][l * 8];
            cv[p] = MFMA32(ah[k0i].s, whiR[fi], cv[p]);
            cv[p] = MFMA32(ah[k0i].s, wlo, cv[p]);
            cv[p] = MFMA32(al[k0i].s, whiR[fi], cv[p]);
          }
        }
      __builtin_amdgcn_s_setprio(0);

      // ---- pack C-regs as K=16 frags (no cross-lane movement needed) ----
      S4 cqh[2], cql[2], ckh[2], ckl[2], va[2];
      #pragma unroll
      for (int p = 0; p < 2; ++p) {
        cqh[p].u[0] = pk_hi(cq[p][0], cq[p][1]);
        cqh[p].u[1] = pk_hi(cq[p][2], cq[p][3]);
        cql[p].u[0] = pk_hi(cq[p][0] - btrunc(cq[p][0]), cq[p][1] - btrunc(cq[p][1]));
        cql[p].u[1] = pk_hi(cq[p][2] - btrunc(cq[p][2]), cq[p][3] - btrunc(cq[p][3]));
        ckh[p].u[0] = pk_hi(ck[p][0], ck[p][1]);
        ckh[p].u[1] = pk_hi(ck[p][2], ck[p][3]);
        ckl[p].u[0] = pk_hi(ck[p][0] - btrunc(ck[p][0]), ck[p][1] - btrunc(ck[p][1]));
        ckl[p].u[1] = pk_hi(ck[p][2] - btrunc(ck[p][2]), ck[p][3] - btrunc(ck[p][3]));
        va[p].u[0] = pk_rnd(cv[p][0], cv[p][1]);
        va[p].u[1] = pk_rnd(cv[p][2], cv[p][3]);
      }

      // ---- energy^T = K Q^T  (A = ck-regs, B = cq-regs) ----
      f32x4 eng = fz;
      #pragma unroll
      for (int p = 0; p < 2; ++p) {
        eng = MFMA16(ckh[p].s, cqh[p].s, eng);
        eng = MFMA16(ckh[p].s, cql[p].s, eng);
        eng = MFMA16(ckl[p].s, cqh[p].s, eng);
      }
      // lane holds energy^T[s=4g+r][t=c]

      // ---- softmax over s ----
      float w[4];
      {
        float mloc = -1e30f;
        if (g < 3) {
          mloc = eng[0];
          #pragma unroll
          for (int r = 1; r < 4; ++r) mloc = fmaxf(mloc, eng[r]);
        }
        float mx = mloc;
        mx = fmaxf(mx, __shfl_xor(mx, 16));
        mx = fmaxf(mx, __shfl_xor(mx, 32));
        float sloc = 0.f;
        #pragma unroll
        for (int r = 0; r < 4; ++r) {
          w[r] = (g < 3) ? __expf(eng[r] - mx) : 0.f;
          sloc += w[r];
        }
        float sm = sloc;
        sm += __shfl_xor(sm, 16);
        sm += __shfl_xor(sm, 32);
        float inv = 1.f / sm;
        #pragma unroll
        for (int r = 0; r < 4; ++r) w[r] *= inv;
      }

      // ---- ha^T = V^T attn^T  (A = cv-regs, B = w-regs) ----
      S4 wh_, wl_;
      wh_.u[0] = pk_hi(w[0], w[1]);
      wh_.u[1] = pk_hi(w[2], w[3]);
      wl_.u[0] = pk_hi(w[0] - btrunc(w[0]), w[1] - btrunc(w[1]));
      wl_.u[1] = pk_hi(w[2] - btrunc(w[2]), w[3] - btrunc(w[3]));
      f32x4 hat[2];
      #pragma unroll
      for (int p = 0; p < 2; ++p) {
        hat[p] = MFMA16(va[p].s, wh_.s, fz);
        hat[p] = MFMA16(va[p].s, wl_.s, hat[p]);
      }

      // ---- mem scores^T (VALU via precomputed G) ----
      float sc0[4], sc1[4];
      #pragma unroll
      for (int r = 0; r < 4; ++r) {
        const float* Gp = &Glds[4 * g + r][0];
        sc0[r] = pcur[0] * Gp[0] + pcur[1] * Gp[1] + pcur[2] * Gp[2];
        const float* Gq = &Glds[16 + 4 * g + r][0];
        sc1[r] = pcur[0] * Gq[0] + pcur[1] * Gq[1] + pcur[2] * Gq[2];
      }
      float w0[4], w1[4];
      {
        float mloc = sc0[0];
        #pragma unroll
        for (int r = 1; r < 4; ++r) mloc = fmaxf(mloc, sc0[r]);
        if (g == 0) {
          #pragma unroll
          for (int r = 0; r < 4; ++r) mloc = fmaxf(mloc, sc1[r]);
        }
        float mx = mloc;
        mx = fmaxf(mx, __shfl_xor(mx, 16));
        mx = fmaxf(mx, __shfl_xor(mx, 32));
        float sloc = 0.f;
        #pragma unroll
        for (int r = 0; r < 4; ++r) {
          w0[r] = __expf(sc0[r] - mx); sloc += w0[r];
          w1[r] = (g == 0) ? __expf(sc1[r] - mx) : 0.f; sloc += w1[r];
        }
        float sm = sloc;
        sm += __shfl_xor(sm, 16);
        sm += __shfl_xor(sm, 32);
        float inv = 1.f / sm;
        #pragma unroll
        for (int r = 0; r < 4; ++r) { w0[r] *= inv; w1[r] *= inv; }
      }

      // ---- memories^T = memw^T attnw^T  (A = mw-regs, B = w0/w1-regs) ----
      S4 w0h, w0l, w1h, w1l;
      w0h.u[0] = pk_hi(w0[0], w0[1]);  w0h.u[1] = pk_hi(w0[2], w0[3]);
      w0l.u[0] = pk_hi(w0[0] - btrunc(w0[0]), w0[1] - btrunc(w0[1]));
      w0l.u[1] = pk_hi(w0[2] - btrunc(w0[2]), w0[3] - btrunc(w0[3]));
      w1h.u[0] = pk_hi(w1[0], w1[1]);  w1h.u[1] = pk_hi(w1[2], w1[3]);
      w1l.u[0] = pk_hi(w1[0] - btrunc(w1[0]), w1[1] - btrunc(w1[1]));
      w1l.u[1] = pk_hi(w1[2] - btrunc(w1[2]), w1[3] - btrunc(w1[3]));
      f32x4 cmem[2];
      #pragma unroll
      for (int p = 0; p < 2; ++p) {
        cmem[p] = MFMA16(mwh[p][0].s, w0h.s, fz);
        cmem[p] = MFMA16(mwh[p][0].s, w0l.s, cmem[p]);
        cmem[p] = MFMA16(mwl[p][0].s, w0h.s, cmem[p]);
        cmem[p] = MFMA16(mwh[p][1].s, w1h.s, cmem[p]);
        cmem[p] = MFMA16(mwh[p][1].s, w1l.s, cmem[p]);
        cmem[p] = MFMA16(mwl[p][1].s, w1h.s, cmem[p]);
      }

      // ---- cosine similarity over m, store at g==0 ----
      float dot = 0.f, na = 0.f, nb = 0.f;
      #pragma unroll
      for (int p = 0; p < 2; ++p)
        #pragma unroll
        for (int r = 0; r < 4; ++r) {
          float a = cmem[p][r], h = hat[p][r];
          dot += a * h; na += a * a; nb += h * h;
        }
      dot += __shfl_xor(dot, 16); dot += __shfl_xor(dot, 32);
      na  += __shfl_xor(na, 16);  na  += __shfl_xor(na, 32);
      nb  += __shfl_xor(nb, 16);  nb  += __shfl_xor(nb, 32);
      if (g == 0 && c < kT) {
        float cvv = dot / fmaxf(sqrtf(na) * sqrtf(nb), 1e-8f);
        out[(size_t)site * (kT * kE) + c * kE + e] = cvv;
      }
    }

    #pragma unroll
    for (int j = 0; j < 16; ++j) hcur[j] = hnxt[j];
    pcur[0] = pnxt[0]; pcur[1] = pnxt[1]; pcur[2] = pnxt[2];
    site = nsite;
  }
}

}  // namespace

extern "C" void kernel_launch(void* const* d_in, const int* in_sizes, int n_in,
                              void* d_out, int out_size, void* d_ws, size_t ws_size,
                              hipStream_t stream) {
  const float* input = (const float*)d_in[0];
  const float* h0    = (const float*)d_in[1];
  const float* h1    = (const float*)d_in[2];
  const float* h2    = (const float*)d_in[3];
  const float* memw  = (const float*)d_in[4];
  const float* iq    = (const float*)d_in[5];
  const float* hq    = (const float*)d_in[6];
  const float* kw    = (const float*)d_in[7];
  const float* vw    = (const float*)d_in[8];
  float* out = (float*)d_out;

  testam_mfma<<<kE * kNB, kThreads, 0, stream>>>(
      input, h0, h1, h2, memw, iq, hq, kw, vw, out);
}

// Round 13
// 76.374 us; speedup vs baseline: 1.1746x; 1.1746x over previous
//
#include <hip/hip_runtime.h>
#include <math.h>

typedef __attribute__((ext_vector_type(8))) short short8;
typedef __attribute__((ext_vector_type(4))) short short4v;
typedef __attribute__((ext_vector_type(4))) float f32x4;

namespace {

constexpr int kT = 12, kMS = 20, kE = 3;
constexpr int kSites = 64 * 325;                 // 20800
constexpr int kWaves = 8;
constexpr int kThreads = kWaves * 64;            // 512
constexpr int kNB = 340;                         // blocks per expert (1020 total ~ 4/CU)
constexpr int kStride = kNB * kWaves;            // 2720
constexpr int kIters = (kSites + kStride - 1) / kStride;  // 8

__device__ __forceinline__ void split1(float x, unsigned& hi, unsigned& lo) {
  unsigned u = __float_as_uint(x);
  hi = u >> 16;
  float r = x - __uint_as_float(u & 0xFFFF0000u);   // exact (Sterbenz)
  lo = __float_as_uint(r) >> 16;
}
__device__ __forceinline__ float btrunc(float x) {
  return __uint_as_float(__float_as_uint(x) & 0xFFFF0000u);
}
__device__ __forceinline__ unsigned pk_hi(float a, float b) {   // {bf(b):bf(a)}, a low
  return __builtin_amdgcn_perm(__float_as_uint(b), __float_as_uint(a), 0x07060302u);
}
__device__ __forceinline__ unsigned pk_rnd(float a, float b) {  // round-half-up bf16 pack
  return __builtin_amdgcn_perm(__float_as_uint(b) + 0x8000u,
                               __float_as_uint(a) + 0x8000u, 0x07060302u);
}

union S8 { short8 s; unsigned u[4]; };
union S4 { short4v s; unsigned u[2]; };

#define MFMA32(a, b, c) __builtin_amdgcn_mfma_f32_16x16x32_bf16((a), (b), (c), 0, 0, 0)
// gfx90a+ name on gfx950 (v_mfma_f32_16x16x16_bf16; A/B = 2 VGPR = 4 bf16).
// No __has_builtin guard — false in the HIP host pass (R10 lesson).
#define MFMA16(a, b, c) __builtin_amdgcn_mfma_f32_16x16x16bf16_1k((a), (b), (c), 0, 0, 0)

// Layouts (m89-verified K=32; classic K=16):
//   K=32 A: lane holds A[row=l&15][k=8g+j]; B: B[k=8g+j][col=l&15]
//   K=16 A: lane holds A[row=l&15][k=4g+j]; B: B[k=4g+j][col=l&15]
//   C/D (both): lane holds D[row=4g+r][col=l&15]
// => C-regs of X == A-frag(K=16) of X^T == B-frag(K=16) of X.  (zero-move chaining)
// NOTE (R12 lesson): do NOT hoist the 12 weight frags to registers — +48 VGPR
// liveness makes the allocator spill to scratch (WRITE_SIZE 8.8->37 MB, -15 us).
__global__ __launch_bounds__(kThreads, 4) void testam_mfma(
    const float* __restrict__ input, const float* __restrict__ h0,
    const float* __restrict__ h1, const float* __restrict__ h2,
    const float* __restrict__ memw, const float* __restrict__ iq,
    const float* __restrict__ hq, const float* __restrict__ kwt,
    const float* __restrict__ vw, float* __restrict__ out) {

  __shared__ __align__(16) unsigned short wlds[2][12][512];  // Wq^T/Wk^T A-frags, Wv B-frags
  __shared__ __align__(16) float Glds[32][4];                // G^T = (iq@memw^T)^T padded

  const int tid = threadIdx.x;
  const int e = blockIdx.x / kNB;
  const int b = blockIdx.x % kNB;
  const int l = tid & 63, wv = tid >> 6;
  const int g = l >> 4, c = l & 15;

  // ---- one-time staging: QKV weight frags (K=32) into LDS ----
  for (int idx = tid; idx < 768; idx += kThreads) {
    int ll = idx & 63, fi = idx >> 6;
    int mat = fi >> 2, x = (fi >> 1) & 1, y = fi & 1;
    int gg = ll >> 4, cc = ll & 15;
    const float* wp = ((mat == 0) ? hq : (mat == 1) ? kwt : vw) + e * 2048
                      + (y * 32 + gg * 8) * 32 + x * 16 + cc;
    short8 sh, sl;
    #pragma unroll
    for (int j = 0; j < 8; ++j) {
      unsigned h, lo; split1(wp[j * 32], h, lo);
      sh[j] = (short)h; sl[j] = (short)lo;
    }
    *(short8*)&wlds[0][fi][ll * 8] = sh;
    *(short8*)&wlds[1][fi][ll * 8] = sl;
  }
  for (int idx = tid; idx < 128; idx += kThreads) {
    int s = idx >> 2, d = idx & 3;
    float acc = 0.f;
    if (d < 3 && s < kMS) {
      for (int m = 0; m < 32; ++m) acc += iq[d * 32 + m] * memw[s * 32 + m];
    }
    Glds[s][d] = acc;
  }

  // ---- memw^T A-frags (K=16) straight into registers (once) ----
  S4 mwh[2][2], mwl[2][2];
  #pragma unroll
  for (int p = 0; p < 2; ++p)
    #pragma unroll
    for (int sch = 0; sch < 2; ++sch) {
      float v[4];
      #pragma unroll
      for (int j = 0; j < 4; ++j) {
        int s = 16 * sch + 4 * g + j;
        v[j] = (s < kMS) ? memw[s * 32 + 16 * p + c] : 0.f;
      }
      mwh[p][sch].u[0] = pk_hi(v[0], v[1]);
      mwh[p][sch].u[1] = pk_hi(v[2], v[3]);
      mwl[p][sch].u[0] = pk_hi(v[0] - btrunc(v[0]), v[1] - btrunc(v[1]));
      mwl[p][sch].u[1] = pk_hi(v[2] - btrunc(v[2]), v[3] - btrunc(v[3]));
    }
  __syncthreads();

  const float* hbase = (e == 0) ? h0 : (e == 1) ? h1 : h2;
  const f32x4 fz = {0.f, 0.f, 0.f, 0.f};

  // lanes c>=12 read row 0 (finite); s>=12 slots meet exact-zero weights.
  const int crow = (c < kT) ? c : 0;

  float hcur[16], hnxt[16];
  float pcur[3], pnxt[3];

  auto load_site = [&](int s, float* hr, float* pr) {
    const int sc_ = (s < kSites) ? s : (kSites - 1);
    const float* p = hbase + (size_t)sc_ * 768 + crow * 64 + g * 8;
    #pragma unroll
    for (int k0i = 0; k0i < 2; ++k0i)
      #pragma unroll
      for (int j = 0; j < 8; ++j) hr[k0i * 8 + j] = p[k0i * 32 + j];
    const float* ip = input + (size_t)sc_ * 36 + crow * 3;
    pr[0] = ip[0]; pr[1] = ip[1]; pr[2] = ip[2];
  };

  int site = b * kWaves + wv;
  load_site(site, hcur, pcur);

  for (int it = 0; it < kIters; ++it) {
    const int nsite = site + kStride;
    load_site(nsite, hnxt, pnxt);

    if (site < kSites) {
      // ---- h A-frags (double as h^T B-frags), K=32 ----
      S8 ah[2], al[2];
      #pragma unroll
      for (int k0i = 0; k0i < 2; ++k0i)
        #pragma unroll
        for (int jj = 0; jj < 4; ++jj) {
          float a = hcur[k0i * 8 + 2 * jj], bb = hcur[k0i * 8 + 2 * jj + 1];
          ah[k0i].u[jj] = pk_hi(a, bb);
          al[k0i].u[jj] = pk_hi(a - btrunc(a), bb - btrunc(bb));
        }

      // ---- Q^T, K^T (swapped, A=W^T), V (direct); 3-term bf16x3 ----
      // (6 independent accumulator chains -> ILP already sufficient here)
      f32x4 cq[2] = {fz, fz}, ck[2] = {fz, fz}, cv[2] = {fz, fz};
      __builtin_amdgcn_s_setprio(1);
      #pragma unroll
      for (int p = 0; p < 2; ++p)
        #pragma unroll
        for (int k0i = 0; k0i < 2; ++k0i) {
          {
            const int fi = 0 + p * 2 + k0i;
            short8 wh = *(const short8*)&wlds[0][fi][l * 8];
            short8 wlo = *(const short8*)&wlds[1][fi][l * 8];
            cq[p] = MFMA32(wh, ah[k0i].s, cq[p]);
            cq[p] = MFMA32(wh, al[k0i].s, cq[p]);
            cq[p] = MFMA32(wlo, ah[k0i].s, cq[p]);
          }
          {
            const int fi = 4 + p * 2 + k0i;
            short8 wh = *(const short8*)&wlds[0][fi][l * 8];
            short8 wlo = *(const short8*)&wlds[1][fi][l * 8];
            ck[p] = MFMA32(wh, ah[k0i].s, ck[p]);
            ck[p] = MFMA32(wh, al[k0i].s, ck[p]);
            ck[p] = MFMA32(wlo, ah[k0i].s, ck[p]);
          }
          {
            const int fi = 8 + p * 2 + k0i;
            short8 wh = *(const short8*)&wlds[0][fi][l * 8];
            short8 wlo = *(const short8*)&wlds[1][fi][l * 8];
            cv[p] = MFMA32(ah[k0i].s, wh, cv[p]);
            cv[p] = MFMA32(ah[k0i].s, wlo, cv[p]);
            cv[p] = MFMA32(al[k0i].s, wh, cv[p]);
          }
        }
      __builtin_amdgcn_s_setprio(0);

      // ---- pack C-regs as K=16 frags (no cross-lane movement needed) ----
      S4 cqh[2], cql[2], ckh[2], ckl[2], va[2];
      #pragma unroll
      for (int p = 0; p < 2; ++p) {
        cqh[p].u[0] = pk_hi(cq[p][0], cq[p][1]);
        cqh[p].u[1] = pk_hi(cq[p][2], cq[p][3]);
        cql[p].u[0] = pk_hi(cq[p][0] - btrunc(cq[p][0]), cq[p][1] - btrunc(cq[p][1]));
        cql[p].u[1] = pk_hi(cq[p][2] - btrunc(cq[p][2]), cq[p][3] - btrunc(cq[p][3]));
        ckh[p].u[0] = pk_hi(ck[p][0], ck[p][1]);
        ckh[p].u[1] = pk_hi(ck[p][2], ck[p][3]);
        ckl[p].u[0] = pk_hi(ck[p][0] - btrunc(ck[p][0]), ck[p][1] - btrunc(ck[p][1]));
        ckl[p].u[1] = pk_hi(ck[p][2] - btrunc(ck[p][2]), ck[p][3] - btrunc(ck[p][3]));
        va[p].u[0] = pk_rnd(cv[p][0], cv[p][1]);
        va[p].u[1] = pk_rnd(cv[p][2], cv[p][3]);
      }

      // ---- energy^T = K Q^T : split into two independent 3-chains (latency) ----
      f32x4 engA = fz, engB = fz;
      engA = MFMA16(ckh[0].s, cqh[0].s, engA);
      engA = MFMA16(ckh[0].s, cql[0].s, engA);
      engA = MFMA16(ckl[0].s, cqh[0].s, engA);
      engB = MFMA16(ckh[1].s, cqh[1].s, engB);
      engB = MFMA16(ckh[1].s, cql[1].s, engB);
      engB = MFMA16(ckl[1].s, cqh[1].s, engB);
      f32x4 eng = engA + engB;
      // lane holds energy^T[s=4g+r][t=c]

      // ---- softmax over s ----
      float w[4];
      {
        float mloc = -1e30f;
        if (g < 3) {
          mloc = eng[0];
          #pragma unroll
          for (int r = 1; r < 4; ++r) mloc = fmaxf(mloc, eng[r]);
        }
        float mx = mloc;
        mx = fmaxf(mx, __shfl_xor(mx, 16));
        mx = fmaxf(mx, __shfl_xor(mx, 32));
        float sloc = 0.f;
        #pragma unroll
        for (int r = 0; r < 4; ++r) {
          w[r] = (g < 3) ? __expf(eng[r] - mx) : 0.f;
          sloc += w[r];
        }
        float sm = sloc;
        sm += __shfl_xor(sm, 16);
        sm += __shfl_xor(sm, 32);
        float inv = 1.f / sm;
        #pragma unroll
        for (int r = 0; r < 4; ++r) w[r] *= inv;
      }

      // ---- ha^T = V^T attn^T  (A = cv-regs, B = w-regs) ----
      S4 wh_, wl_;
      wh_.u[0] = pk_hi(w[0], w[1]);
      wh_.u[1] = pk_hi(w[2], w[3]);
      wl_.u[0] = pk_hi(w[0] - btrunc(w[0]), w[1] - btrunc(w[1]));
      wl_.u[1] = pk_hi(w[2] - btrunc(w[2]), w[3] - btrunc(w[3]));
      f32x4 hat[2];
      #pragma unroll
      for (int p = 0; p < 2; ++p) {
        hat[p] = MFMA16(va[p].s, wh_.s, fz);
        hat[p] = MFMA16(va[p].s, wl_.s, hat[p]);
      }

      // ---- mem scores^T (VALU via precomputed G) ----
      float sc0[4], sc1[4];
      #pragma unroll
      for (int r = 0; r < 4; ++r) {
        const float* Gp = &Glds[4 * g + r][0];
        sc0[r] = pcur[0] * Gp[0] + pcur[1] * Gp[1] + pcur[2] * Gp[2];
        const float* Gq = &Glds[16 + 4 * g + r][0];
        sc1[r] = pcur[0] * Gq[0] + pcur[1] * Gq[1] + pcur[2] * Gq[2];
      }
      float w0[4], w1[4];
      {
        float mloc = sc0[0];
        #pragma unroll
        for (int r = 1; r < 4; ++r) mloc = fmaxf(mloc, sc0[r]);
        if (g == 0) {
          #pragma unroll
          for (int r = 0; r < 4; ++r) mloc = fmaxf(mloc, sc1[r]);
        }
        float mx = mloc;
        mx = fmaxf(mx, __shfl_xor(mx, 16));
        mx = fmaxf(mx, __shfl_xor(mx, 32));
        float sloc = 0.f;
        #pragma unroll
        for (int r = 0; r < 4; ++r) {
          w0[r] = __expf(sc0[r] - mx); sloc += w0[r];
          w1[r] = (g == 0) ? __expf(sc1[r] - mx) : 0.f; sloc += w1[r];
        }
        float sm = sloc;
        sm += __shfl_xor(sm, 16);
        sm += __shfl_xor(sm, 32);
        float inv = 1.f / sm;
        #pragma unroll
        for (int r = 0; r < 4; ++r) { w0[r] *= inv; w1[r] *= inv; }
      }

      // ---- memories^T = memw^T attnw^T : per p, two independent 3-chains ----
      S4 w0h, w0l, w1h, w1l;
      w0h.u[0] = pk_hi(w0[0], w0[1]);  w0h.u[1] = pk_hi(w0[2], w0[3]);
      w0l.u[0] = pk_hi(w0[0] - btrunc(w0[0]), w0[1] - btrunc(w0[1]));
      w0l.u[1] = pk_hi(w0[2] - btrunc(w0[2]), w0[3] - btrunc(w0[3]));
      w1h.u[0] = pk_hi(w1[0], w1[1]);  w1h.u[1] = pk_hi(w1[2], w1[3]);
      w1l.u[0] = pk_hi(w1[0] - btrunc(w1[0]), w1[1] - btrunc(w1[1]));
      w1l.u[1] = pk_hi(w1[2] - btrunc(w1[2]), w1[3] - btrunc(w1[3]));
      f32x4 cmem[2];
      #pragma unroll
      for (int p = 0; p < 2; ++p) {
        f32x4 cmA = fz, cmB = fz;
        cmA = MFMA16(mwh[p][0].s, w0h.s, cmA);
        cmA = MFMA16(mwh[p][0].s, w0l.s, cmA);
        cmA = MFMA16(mwl[p][0].s, w0h.s, cmA);
        cmB = MFMA16(mwh[p][1].s, w1h.s, cmB);
        cmB = MFMA16(mwh[p][1].s, w1l.s, cmB);
        cmB = MFMA16(mwl[p][1].s, w1h.s, cmB);
        cmem[p] = cmA + cmB;
      }

      // ---- cosine similarity over m, store at g==0 ----
      float dot = 0.f, na = 0.f, nb = 0.f;
      #pragma unroll
      for (int p = 0; p < 2; ++p)
        #pragma unroll
        for (int r = 0; r < 4; ++r) {
          float a = cmem[p][r], h = hat[p][r];
          dot += a * h; na += a * a; nb += h * h;
        }
      dot += __shfl_xor(dot, 16); dot += __shfl_xor(dot, 32);
      na  += __shfl_xor(na, 16);  na  += __shfl_xor(na, 32);
      nb  += __shfl_xor(nb, 16);  nb  += __shfl_xor(nb, 32);
      if (g == 0 && c < kT) {
        float cvv = dot / fmaxf(sqrtf(na) * sqrtf(nb), 1e-8f);
        out[(size_t)site * (kT * kE) + c * kE + e] = cvv;
      }
    }

    #pragma unroll
    for (int j = 0; j < 16; ++j) hcur[j] = hnxt[j];
    pcur[0] = pnxt[0]; pcur[1] = pnxt[1]; pcur[2] = pnxt[2];
    site = nsite;
  }
}

}  // namespace

extern "C" void kernel_launch(void* const* d_in, const int* in_sizes, int n_in,
                              void* d_out, int out_size, void* d_ws, size_t ws_size,
                              hipStream_t stream) {
  const float* input = (const float*)d_in[0];
  const float* h0    = (const float*)d_in[1];
  const float* h1    = (const float*)d_in[2];
  const float* h2    = (const float*)d_in[3];
  const float* memw  = (const float*)d_in[4];
  const float* iq    = (const float*)d_in[5];
  const float* hq    = (const float*)d_in[6];
  const float* kw    = (const float*)d_in[7];
  const float* vw    = (const float*)d_in[8];
  float* out = (float*)d_out;

  testam_mfma<<<kE * kNB, kThreads, 0, stream>>>(
      input, h0, h1, h2, memw, iq, hq, kw, vw, out);
}

// Round 17
// 74.323 us; speedup vs baseline: 1.2070x; 1.0276x over previous
//
#include <hip/hip_runtime.h>
#include <math.h>

typedef __attribute__((ext_vector_type(8))) short short8;
typedef __attribute__((ext_vector_type(4))) short short4v;
typedef __attribute__((ext_vector_type(4))) float f32x4;

namespace {

constexpr int kT = 12, kMS = 20, kE = 3;
constexpr int kSites = 64 * 325;                 // 20800
constexpr int kWaves = 8;
constexpr int kThreads = kWaves * 64;            // 512
constexpr int kNB = 340;                         // blocks per expert (1020 total ~ 4/CU)
constexpr int kStride = kNB * kWaves;            // 2720
constexpr int kIters = (kSites + kStride - 1) / kStride;  // 8 (even -> clean unroll-2)

__device__ __forceinline__ void split1(float x, unsigned& hi, unsigned& lo) {
  unsigned u = __float_as_uint(x);
  hi = u >> 16;
  float r = x - __uint_as_float(u & 0xFFFF0000u);   // exact (Sterbenz)
  lo = __float_as_uint(r) >> 16;
}
__device__ __forceinline__ float btrunc(float x) {
  return __uint_as_float(__float_as_uint(x) & 0xFFFF0000u);
}
__device__ __forceinline__ unsigned pk_hi(float a, float b) {   // {bf(b):bf(a)}, a low
  return __builtin_amdgcn_perm(__float_as_uint(b), __float_as_uint(a), 0x07060302u);
}
__device__ __forceinline__ unsigned pk_rnd(float a, float b) {  // round-half-up bf16 pack
  return __builtin_amdgcn_perm(__float_as_uint(b) + 0x8000u,
                               __float_as_uint(a) + 0x8000u, 0x07060302u);
}

union S8 { short8 s; unsigned u[4]; };
union S4 { short4v s; unsigned u[2]; };

#define MFMA32(a, b, c) __builtin_amdgcn_mfma_f32_16x16x32_bf16((a), (b), (c), 0, 0, 0)
// gfx90a+ name on gfx950. No __has_builtin guard — false in the HIP host pass (R10).
#define MFMA16(a, b, c) __builtin_amdgcn_mfma_f32_16x16x16bf16_1k((a), (b), (c), 0, 0, 0)

// Layouts (m89-verified K=32; classic K=16):
//   K=32 A: lane holds A[row=l&15][k=8g+j]; B: B[k=8g+j][col=l&15]
//   K=16 A: lane holds A[row=l&15][k=4g+j]; B: B[k=4g+j][col=l&15]
//   C/D (both): lane holds D[row=4g+r][col=l&15]
// => C-regs of X == A-frag(K=16) of X^T == B-frag(K=16) of X.  (zero-move chaining)
// R12 lesson: do NOT hoist the 12 weight frags to regs (+48 VGPR -> scratch spill).
// R13 lesson: MFMA chain-splitting is neutral — latency already hidden by TLP.
__global__ __launch_bounds__(kThreads, 4) void testam_mfma(
    const float* __restrict__ input, const float* __restrict__ h0,
    const float* __restrict__ h1, const float* __restrict__ h2,
    const float* __restrict__ memw, const float* __restrict__ iq,
    const float* __restrict__ hq, const float* __restrict__ kwt,
    const float* __restrict__ vw, float* __restrict__ out) {

  __shared__ __align__(16) unsigned short wlds[2][12][512];  // Wq^T/Wk^T A-frags, Wv B-frags
  __shared__ __align__(16) float Glds[32][4];                // G^T = (iq@memw^T)^T padded

  const int tid = threadIdx.x;
  const int e = blockIdx.x / kNB;
  const int b = blockIdx.x % kNB;
  const int l = tid & 63, wv = tid >> 6;
  const int g = l >> 4, c = l & 15;

  // ---- one-time staging: QKV weight frags (K=32) into LDS ----
  for (int idx = tid; idx < 768; idx += kThreads) {
    int ll = idx & 63, fi = idx >> 6;
    int mat = fi >> 2, x = (fi >> 1) & 1, y = fi & 1;
    int gg = ll >> 4, cc = ll & 15;
    const float* wp = ((mat == 0) ? hq : (mat == 1) ? kwt : vw) + e * 2048
                      + (y * 32 + gg * 8) * 32 + x * 16 + cc;
    short8 sh, sl;
    #pragma unroll
    for (int j = 0; j < 8; ++j) {
      unsigned h, lo; split1(wp[j * 32], h, lo);
      sh[j] = (short)h; sl[j] = (short)lo;
    }
    *(short8*)&wlds[0][fi][ll * 8] = sh;
    *(short8*)&wlds[1][fi][ll * 8] = sl;
  }
  for (int idx = tid; idx < 128; idx += kThreads) {
    int s = idx >> 2, d = idx & 3;
    float acc = 0.f;
    if (d < 3 && s < kMS) {
      for (int m = 0; m < 32; ++m) acc += iq[d * 32 + m] * memw[s * 32 + m];
    }
    Glds[s][d] = acc;
  }

  // ---- memw^T A-frags (K=16) straight into registers (once) ----
  S4 mwh[2][2], mwl[2][2];
  #pragma unroll
  for (int p = 0; p < 2; ++p)
    #pragma unroll
    for (int sch = 0; sch < 2; ++sch) {
      float v[4];
      #pragma unroll
      for (int j = 0; j < 4; ++j) {
        int s = 16 * sch + 4 * g + j;
        v[j] = (s < kMS) ? memw[s * 32 + 16 * p + c] : 0.f;
      }
      mwh[p][sch].u[0] = pk_hi(v[0], v[1]);
      mwh[p][sch].u[1] = pk_hi(v[2], v[3]);
      mwl[p][sch].u[0] = pk_hi(v[0] - btrunc(v[0]), v[1] - btrunc(v[1]));
      mwl[p][sch].u[1] = pk_hi(v[2] - btrunc(v[2]), v[3] - btrunc(v[3]));
    }
  __syncthreads();

  const float* hbase = (e == 0) ? h0 : (e == 1) ? h1 : h2;
  const f32x4 fz = {0.f, 0.f, 0.f, 0.f};

  // lanes c>=12 read row 0 (finite); s>=12 slots meet exact-zero weights.
  const int crow = (c < kT) ? c : 0;

  auto load_site = [&](int s, float* hr, float* pr) {
    const int sc_ = (s < kSites) ? s : (kSites - 1);
    const float* p = hbase + (size_t)sc_ * 768 + crow * 64 + g * 8;
    *(f32x4*)&hr[0]  = *(const f32x4*)&p[0];    // 16B-aligned: site*768+c*64+g*8
    *(f32x4*)&hr[4]  = *(const f32x4*)&p[4];
    *(f32x4*)&hr[8]  = *(const f32x4*)&p[32];
    *(f32x4*)&hr[12] = *(const f32x4*)&p[36];
    const float* ip = input + (size_t)sc_ * 36 + crow * 3;
    pr[0] = ip[0]; pr[1] = ip[1]; pr[2] = ip[2];
  };

  auto body = [&](int site, const float* hv, const float* pv) {
    // ---- h A-frags (double as h^T B-frags), K=32 ----
    S8 ah[2], al[2];
    #pragma unroll
    for (int k0i = 0; k0i < 2; ++k0i)
      #pragma unroll
      for (int jj = 0; jj < 4; ++jj) {
        float a = hv[k0i * 8 + 2 * jj], bb = hv[k0i * 8 + 2 * jj + 1];
        ah[k0i].u[jj] = pk_hi(a, bb);
        al[k0i].u[jj] = pk_hi(a - btrunc(a), bb - btrunc(bb));
      }

    // ---- Q^T, K^T (swapped, A=W^T), V (direct); 3-term bf16x3 ----
    f32x4 cq[2] = {fz, fz}, ck[2] = {fz, fz}, cv[2] = {fz, fz};
    __builtin_amdgcn_s_setprio(1);
    #pragma unroll
    for (int p = 0; p < 2; ++p)
      #pragma unroll
      for (int k0i = 0; k0i < 2; ++k0i) {
        {
          const int fi = 0 + p * 2 + k0i;
          short8 wh = *(const short8*)&wlds[0][fi][l * 8];
          short8 wlo = *(const short8*)&wlds[1][fi][l * 8];
          cq[p] = MFMA32(wh, ah[k0i].s, cq[p]);
          cq[p] = MFMA32(wh, al[k0i].s, cq[p]);
          cq[p] = MFMA32(wlo, ah[k0i].s, cq[p]);
        }
        {
          const int fi = 4 + p * 2 + k0i;
          short8 wh = *(const short8*)&wlds[0][fi][l * 8];
          short8 wlo = *(const short8*)&wlds[1][fi][l * 8];
          ck[p] = MFMA32(wh, ah[k0i].s, ck[p]);
          ck[p] = MFMA32(wh, al[k0i].s, ck[p]);
          ck[p] = MFMA32(wlo, ah[k0i].s, ck[p]);
        }
        {
          const int fi = 8 + p * 2 + k0i;
          short8 wh = *(const short8*)&wlds[0][fi][l * 8];
          short8 wlo = *(const short8*)&wlds[1][fi][l * 8];
          cv[p] = MFMA32(ah[k0i].s, wh, cv[p]);
          cv[p] = MFMA32(ah[k0i].s, wlo, cv[p]);
          cv[p] = MFMA32(al[k0i].s, wh, cv[p]);
        }
      }
    __builtin_amdgcn_s_setprio(0);

    // ---- pack C-regs as K=16 frags (no cross-lane movement needed) ----
    S4 cqh[2], cql[2], ckh[2], ckl[2], va[2];
    #pragma unroll
    for (int p = 0; p < 2; ++p) {
      cqh[p].u[0] = pk_hi(cq[p][0], cq[p][1]);
      cqh[p].u[1] = pk_hi(cq[p][2], cq[p][3]);
      cql[p].u[0] = pk_hi(cq[p][0] - btrunc(cq[p][0]), cq[p][1] - btrunc(cq[p][1]));
      cql[p].u[1] = pk_hi(cq[p][2] - btrunc(cq[p][2]), cq[p][3] - btrunc(cq[p][3]));
      ckh[p].u[0] = pk_hi(ck[p][0], ck[p][1]);
      ckh[p].u[1] = pk_hi(ck[p][2], ck[p][3]);
      ckl[p].u[0] = pk_hi(ck[p][0] - btrunc(ck[p][0]), ck[p][1] - btrunc(ck[p][1]));
      ckl[p].u[1] = pk_hi(ck[p][2] - btrunc(ck[p][2]), ck[p][3] - btrunc(ck[p][3]));
      va[p].u[0] = pk_rnd(cv[p][0], cv[p][1]);
      va[p].u[1] = pk_rnd(cv[p][2], cv[p][3]);
    }

    // ---- energy^T = K Q^T (single accumulator — R13: splitting is neutral) ----
    f32x4 eng = fz;
    #pragma unroll
    for (int p = 0; p < 2; ++p) {
      eng = MFMA16(ckh[p].s, cqh[p].s, eng);
      eng = MFMA16(ckh[p].s, cql[p].s, eng);
      eng = MFMA16(ckl[p].s, cqh[p].s, eng);
    }
    // lane holds energy^T[s=4g+r][t=c]

    // ---- softmax over s ----
    float w[4];
    {
      float mloc = -1e30f;
      if (g < 3) {
        mloc = eng[0];
        #pragma unroll
        for (int r = 1; r < 4; ++r) mloc = fmaxf(mloc, eng[r]);
      }
      float mx = mloc;
      mx = fmaxf(mx, __shfl_xor(mx, 16));
      mx = fmaxf(mx, __shfl_xor(mx, 32));
      float sloc = 0.f;
      #pragma unroll
      for (int r = 0; r < 4; ++r) {
        w[r] = (g < 3) ? __expf(eng[r] - mx) : 0.f;
        sloc += w[r];
      }
      float sm = sloc;
      sm += __shfl_xor(sm, 16);
      sm += __shfl_xor(sm, 32);
      float inv = 1.f / sm;
      #pragma unroll
      for (int r = 0; r < 4; ++r) w[r] *= inv;
    }

    // ---- ha^T = V^T attn^T  (A = cv-regs, B = w-regs) ----
    S4 wh_, wl_;
    wh_.u[0] = pk_hi(w[0], w[1]);
    wh_.u[1] = pk_hi(w[2], w[3]);
    wl_.u[0] = pk_hi(w[0] - btrunc(w[0]), w[1] - btrunc(w[1]));
    wl_.u[1] = pk_hi(w[2] - btrunc(w[2]), w[3] - btrunc(w[3]));
    f32x4 hat[2];
    #pragma unroll
    for (int p = 0; p < 2; ++p) {
      hat[p] = MFMA16(va[p].s, wh_.s, fz);
      hat[p] = MFMA16(va[p].s, wl_.s, hat[p]);
    }

    // ---- mem scores^T via precomputed G (b128 broadcast reads) ----
    float sc0[4], sc1[4];
    #pragma unroll
    for (int r = 0; r < 4; ++r) {
      const f32x4 Gv0 = *(const f32x4*)&Glds[4 * g + r][0];
      sc0[r] = pv[0] * Gv0[0] + pv[1] * Gv0[1] + pv[2] * Gv0[2];
      const f32x4 Gv1 = *(const f32x4*)&Glds[16 + 4 * g + r][0];
      sc1[r] = pv[0] * Gv1[0] + pv[1] * Gv1[1] + pv[2] * Gv1[2];
    }
    float w0[4], w1[4];
    {
      float mloc = sc0[0];
      #pragma unroll
      for (int r = 1; r < 4; ++r) mloc = fmaxf(mloc, sc0[r]);
      if (g == 0) {
        #pragma unroll
        for (int r = 0; r < 4; ++r) mloc = fmaxf(mloc, sc1[r]);
      }
      float mx = mloc;
      mx = fmaxf(mx, __shfl_xor(mx, 16));
      mx = fmaxf(mx, __shfl_xor(mx, 32));
      float sloc = 0.f;
      #pragma unroll
      for (int r = 0; r < 4; ++r) {
        w0[r] = __expf(sc0[r] - mx); sloc += w0[r];
        w1[r] = (g == 0) ? __expf(sc1[r] - mx) : 0.f; sloc += w1[r];
      }
      float sm = sloc;
      sm += __shfl_xor(sm, 16);
      sm += __shfl_xor(sm, 32);
      float inv = 1.f / sm;
      #pragma unroll
      for (int r = 0; r < 4; ++r) { w0[r] *= inv; w1[r] *= inv; }
    }

    // ---- memories^T = memw^T attnw^T  (A = mw-regs, B = w0/w1-regs) ----
    S4 w0h, w0l, w1h, w1l;
    w0h.u[0] = pk_hi(w0[0], w0[1]);  w0h.u[1] = pk_hi(w0[2], w0[3]);
    w0l.u[0] = pk_hi(w0[0] - btrunc(w0[0]), w0[1] - btrunc(w0[1]));
    w0l.u[1] = pk_hi(w0[2] - btrunc(w0[2]), w0[3] - btrunc(w0[3]));
    w1h.u[0] = pk_hi(w1[0], w1[1]);  w1h.u[1] = pk_hi(w1[2], w1[3]);
    w1l.u[0] = pk_hi(w1[0] - btrunc(w1[0]), w1[1] - btrunc(w1[1]));
    w1l.u[1] = pk_hi(w1[2] - btrunc(w1[2]), w1[3] - btrunc(w1[3]));
    f32x4 cmem[2];
    #pragma unroll
    for (int p = 0; p < 2; ++p) {
      cmem[p] = MFMA16(mwh[p][0].s, w0h.s, fz);
      cmem[p] = MFMA16(mwh[p][0].s, w0l.s, cmem[p]);
      cmem[p] = MFMA16(mwl[p][0].s, w0h.s, cmem[p]);
      cmem[p] = MFMA16(mwh[p][1].s, w1h.s, cmem[p]);
      cmem[p] = MFMA16(mwh[p][1].s, w1l.s, cmem[p]);
      cmem[p] = MFMA16(mwl[p][1].s, w1h.s, cmem[p]);
    }

    // ---- cosine similarity over m, store at g==0 ----
    float dot = 0.f, na = 0.f, nb = 0.f;
    #pragma unroll
    for (int p = 0; p < 2; ++p)
      #pragma unroll
      for (int r = 0; r < 4; ++r) {
        float a = cmem[p][r], h = hat[p][r];
        dot += a * h; na += a * a; nb += h * h;
      }
    dot += __shfl_xor(dot, 16); dot += __shfl_xor(dot, 32);
    na  += __shfl_xor(na, 16);  na  += __shfl_xor(na, 32);
    nb  += __shfl_xor(nb, 16);  nb  += __shfl_xor(nb, 32);
    if (g == 0 && c < kT) {
      float cvv = dot / fmaxf(sqrtf(na) * sqrtf(nb), 1e-8f);
      out[(size_t)site * (kT * kE) + c * kE + e] = cvv;
    }
  };

  // ---- unroll-2 double-buffered site sweep (no register copies) ----
  float hA[16], hB[16], pA[3], pB[3];
  int site = b * kWaves + wv;
  load_site(site, hA, pA);
  for (int it = 0; it < kIters; it += 2) {
    load_site(site + kStride, hB, pB);          // prefetch odd site
    if (site < kSites) body(site, hA, pA);
    load_site(site + 2 * kStride, hA, pA);      // prefetch next even site
    const int s2 = site + kStride;
    if (s2 < kSites) body(s2, hB, pB);
    site += 2 * kStride;
  }
}

}  // namespace

extern "C" void kernel_launch(void* const* d_in, const int* in_sizes, int n_in,
                              void* d_out, int out_size, void* d_ws, size_t ws_size,
                              hipStream_t stream) {
  const float* input = (const float*)d_in[0];
  const float* h0    = (const float*)d_in[1];
  const float* h1    = (const float*)d_in[2];
  const float* h2    = (const float*)d_in[3];
  const float* memw  = (const float*)d_in[4];
  const float* iq    = (const float*)d_in[5];
  const float* hq    = (const float*)d_in[6];
  const float* kw    = (const float*)d_in[7];
  const float* vw    = (const float*)d_in[8];
  float* out = (float*)d_out;

  testam_mfma<<<kE * kNB, kThreads, 0, stream>>>(
      input, h0, h1, h2, memw, iq, hq, kw, vw, out);
}

// Round 18
// 67.271 us; speedup vs baseline: 1.3336x; 1.1048x over previous
//
#include <hip/hip_runtime.h>
#include <math.h>

typedef __attribute__((ext_vector_type(8))) short short8;
typedef __attribute__((ext_vector_type(4))) short short4v;
typedef __attribute__((ext_vector_type(4))) float f32x4;

namespace {

constexpr int kT = 12, kMS = 20, kE = 3;
constexpr int kSites = 64 * 325;                 // 20800
constexpr int kWaves = 8;
constexpr int kThreads = kWaves * 64;            // 512
constexpr int kNB = 512;                         // blocks total (2/CU exactly at 72.5KB LDS)
constexpr int kStride = kNB * kWaves;            // 4096
constexpr int kIters = (kSites + kStride - 1) / kStride;  // 6 (even -> unroll-2 clean)

__device__ __forceinline__ void split1(float x, unsigned& hi, unsigned& lo) {
  unsigned u = __float_as_uint(x);
  hi = u >> 16;
  float r = x - __uint_as_float(u & 0xFFFF0000u);   // exact (Sterbenz)
  lo = __float_as_uint(r) >> 16;
}
__device__ __forceinline__ float btrunc(float x) {
  return __uint_as_float(__float_as_uint(x) & 0xFFFF0000u);
}
__device__ __forceinline__ unsigned pk_hi(float a, float b) {   // {bf(b):bf(a)}, a low
  return __builtin_amdgcn_perm(__float_as_uint(b), __float_as_uint(a), 0x07060302u);
}
__device__ __forceinline__ unsigned pk_rnd(float a, float b) {  // round-half-up bf16 pack
  return __builtin_amdgcn_perm(__float_as_uint(b) + 0x8000u,
                               __float_as_uint(a) + 0x8000u, 0x07060302u);
}

union S8 { short8 s; unsigned u[4]; };
union S4 { short4v s; unsigned u[2]; };

#define MFMA32(a, b, c) __builtin_amdgcn_mfma_f32_16x16x32_bf16((a), (b), (c), 0, 0, 0)
// gfx90a+ name on gfx950. No __has_builtin guard — false in the HIP host pass (R10).
#define MFMA16(a, b, c) __builtin_amdgcn_mfma_f32_16x16x16bf16_1k((a), (b), (c), 0, 0, 0)

// Layouts (m89-verified K=32; classic K=16):
//   K=32 A: lane holds A[row=l&15][k=8g+j]; B: B[k=8g+j][col=l&15]
//   K=16 A: lane holds A[row=l&15][k=4g+j]; B: B[k=4g+j][col=l&15]
//   C/D (both): lane holds D[row=4g+r][col=l&15]
// => C-regs of X == A-frag(K=16) of X^T == B-frag(K=16) of X.  (zero-move chaining)
// R12 lesson: do NOT hoist the 12 weight frags to regs (+48 VGPR -> scratch spill).
// R13 lesson: MFMA chain-splitting is neutral — latency already hidden by TLP.
// R18: all 3 experts per block; expert-invariant memory path computed ONCE per site.
__global__ __launch_bounds__(kThreads, 4) void testam_mfma(
    const float* __restrict__ input, const float* __restrict__ h0,
    const float* __restrict__ h1, const float* __restrict__ h2,
    const float* __restrict__ memw, const float* __restrict__ iq,
    const float* __restrict__ hq, const float* __restrict__ kwt,
    const float* __restrict__ vw, float* __restrict__ out) {

  __shared__ __align__(16) unsigned short wlds[kE][2][12][512];  // 72KB: all experts
  __shared__ __align__(16) float Glds[32][4];                    // G^T = (iq@memw^T)^T

  const int tid = threadIdx.x;
  const int b = blockIdx.x;
  const int l = tid & 63, wv = tid >> 6;
  const int g = l >> 4, c = l & 15;

  // ---- one-time staging: 3 experts' QKV weight frags (K=32) into LDS ----
  for (int idx = tid; idx < kE * 768; idx += kThreads) {
    int e2 = idx / 768, rem = idx - e2 * 768;
    int ll = rem & 63, fi = rem >> 6;
    int mat = fi >> 2, x = (fi >> 1) & 1, y = fi & 1;
    int gg = ll >> 4, cc = ll & 15;
    const float* wp = ((mat == 0) ? hq : (mat == 1) ? kwt : vw) + e2 * 2048
                      + (y * 32 + gg * 8) * 32 + x * 16 + cc;
    short8 sh, sl;
    #pragma unroll
    for (int j = 0; j < 8; ++j) {
      unsigned h, lo; split1(wp[j * 32], h, lo);
      sh[j] = (short)h; sl[j] = (short)lo;
    }
    *(short8*)&wlds[e2][0][fi][ll * 8] = sh;
    *(short8*)&wlds[e2][1][fi][ll * 8] = sl;
  }
  for (int idx = tid; idx < 128; idx += kThreads) {
    int s = idx >> 2, d = idx & 3;
    float acc = 0.f;
    if (d < 3 && s < kMS) {
      for (int m = 0; m < 32; ++m) acc += iq[d * 32 + m] * memw[s * 32 + m];
    }
    Glds[s][d] = acc;
  }

  // ---- memw^T A-frags (K=16) straight into registers (once) ----
  S4 mwh[2][2], mwl[2][2];
  #pragma unroll
  for (int p = 0; p < 2; ++p)
    #pragma unroll
    for (int sch = 0; sch < 2; ++sch) {
      float v[4];
      #pragma unroll
      for (int j = 0; j < 4; ++j) {
        int s = 16 * sch + 4 * g + j;
        v[j] = (s < kMS) ? memw[s * 32 + 16 * p + c] : 0.f;
      }
      mwh[p][sch].u[0] = pk_hi(v[0], v[1]);
      mwh[p][sch].u[1] = pk_hi(v[2], v[3]);
      mwl[p][sch].u[0] = pk_hi(v[0] - btrunc(v[0]), v[1] - btrunc(v[1]));
      mwl[p][sch].u[1] = pk_hi(v[2] - btrunc(v[2]), v[3] - btrunc(v[3]));
    }
  __syncthreads();

  const f32x4 fz = {0.f, 0.f, 0.f, 0.f};

  // lanes c>=12 read row 0 (finite); s>=12 slots meet exact-zero weights.
  const int crow = (c < kT) ? c : 0;

  auto load_h = [&](const float* hb, int s, float* hr) {
    const int sc_ = (s < kSites) ? s : (kSites - 1);
    const float* p = hb + (size_t)sc_ * 768 + crow * 64 + g * 8;
    *(f32x4*)&hr[0]  = *(const f32x4*)&p[0];
    *(f32x4*)&hr[4]  = *(const f32x4*)&p[4];
    *(f32x4*)&hr[8]  = *(const f32x4*)&p[32];
    *(f32x4*)&hr[12] = *(const f32x4*)&p[36];
  };
  auto load_p = [&](int s, float* pr) {
    const int sc_ = (s < kSites) ? s : (kSites - 1);
    const float* ip = input + (size_t)sc_ * 36 + crow * 3;
    pr[0] = ip[0]; pr[1] = ip[1]; pr[2] = ip[2];
  };

  // ---- expert-invariant memory path: pv -> cmem[2] (once per site) ----
  auto memfn = [&](const float* pv, f32x4* cmem) {
    float sc0[4], sc1[4];
    #pragma unroll
    for (int r = 0; r < 4; ++r) {
      const f32x4 Gv0 = *(const f32x4*)&Glds[4 * g + r][0];
      sc0[r] = pv[0] * Gv0[0] + pv[1] * Gv0[1] + pv[2] * Gv0[2];
      const f32x4 Gv1 = *(const f32x4*)&Glds[16 + 4 * g + r][0];
      sc1[r] = pv[0] * Gv1[0] + pv[1] * Gv1[1] + pv[2] * Gv1[2];
    }
    float w0[4], w1[4];
    {
      float mloc = sc0[0];
      #pragma unroll
      for (int r = 1; r < 4; ++r) mloc = fmaxf(mloc, sc0[r]);
      if (g == 0) {
        #pragma unroll
        for (int r = 0; r < 4; ++r) mloc = fmaxf(mloc, sc1[r]);
      }
      float mx = mloc;
      mx = fmaxf(mx, __shfl_xor(mx, 16));
      mx = fmaxf(mx, __shfl_xor(mx, 32));
      float sloc = 0.f;
      #pragma unroll
      for (int r = 0; r < 4; ++r) {
        w0[r] = __expf(sc0[r] - mx); sloc += w0[r];
        w1[r] = (g == 0) ? __expf(sc1[r] - mx) : 0.f; sloc += w1[r];
      }
      float sm = sloc;
      sm += __shfl_xor(sm, 16);
      sm += __shfl_xor(sm, 32);
      float inv = 1.f / sm;
      #pragma unroll
      for (int r = 0; r < 4; ++r) { w0[r] *= inv; w1[r] *= inv; }
    }
    S4 w0h, w0l, w1h, w1l;
    w0h.u[0] = pk_hi(w0[0], w0[1]);  w0h.u[1] = pk_hi(w0[2], w0[3]);
    w0l.u[0] = pk_hi(w0[0] - btrunc(w0[0]), w0[1] - btrunc(w0[1]));
    w0l.u[1] = pk_hi(w0[2] - btrunc(w0[2]), w0[3] - btrunc(w0[3]));
    w1h.u[0] = pk_hi(w1[0], w1[1]);  w1h.u[1] = pk_hi(w1[2], w1[3]);
    w1l.u[0] = pk_hi(w1[0] - btrunc(w1[0]), w1[1] - btrunc(w1[1]));
    w1l.u[1] = pk_hi(w1[2] - btrunc(w1[2]), w1[3] - btrunc(w1[3]));
    #pragma unroll
    for (int p = 0; p < 2; ++p) {
      cmem[p] = MFMA16(mwh[p][0].s, w0h.s, fz);
      cmem[p] = MFMA16(mwh[p][0].s, w0l.s, cmem[p]);
      cmem[p] = MFMA16(mwl[p][0].s, w0h.s, cmem[p]);
      cmem[p] = MFMA16(mwh[p][1].s, w1h.s, cmem[p]);
      cmem[p] = MFMA16(mwh[p][1].s, w1l.s, cmem[p]);
      cmem[p] = MFMA16(mwl[p][1].s, w1h.s, cmem[p]);
    }
  };

  // ---- per-(site, expert) attention path + cosine + store ----
  auto body = [&](int site, int e, const float* hv, const f32x4* cmem) {
    S8 ah[2], al[2];
    #pragma unroll
    for (int k0i = 0; k0i < 2; ++k0i)
      #pragma unroll
      for (int jj = 0; jj < 4; ++jj) {
        float a = hv[k0i * 8 + 2 * jj], bb = hv[k0i * 8 + 2 * jj + 1];
        ah[k0i].u[jj] = pk_hi(a, bb);
        al[k0i].u[jj] = pk_hi(a - btrunc(a), bb - btrunc(bb));
      }

    f32x4 cq[2] = {fz, fz}, ck[2] = {fz, fz}, cv[2] = {fz, fz};
    __builtin_amdgcn_s_setprio(1);
    #pragma unroll
    for (int p = 0; p < 2; ++p)
      #pragma unroll
      for (int k0i = 0; k0i < 2; ++k0i) {
        {
          const int fi = 0 + p * 2 + k0i;
          short8 wh = *(const short8*)&wlds[e][0][fi][l * 8];
          short8 wlo = *(const short8*)&wlds[e][1][fi][l * 8];
          cq[p] = MFMA32(wh, ah[k0i].s, cq[p]);
          cq[p] = MFMA32(wh, al[k0i].s, cq[p]);
          cq[p] = MFMA32(wlo, ah[k0i].s, cq[p]);
        }
        {
          const int fi = 4 + p * 2 + k0i;
          short8 wh = *(const short8*)&wlds[e][0][fi][l * 8];
          short8 wlo = *(const short8*)&wlds[e][1][fi][l * 8];
          ck[p] = MFMA32(wh, ah[k0i].s, ck[p]);
          ck[p] = MFMA32(wh, al[k0i].s, ck[p]);
          ck[p] = MFMA32(wlo, ah[k0i].s, ck[p]);
        }
        {
          const int fi = 8 + p * 2 + k0i;
          short8 wh = *(const short8*)&wlds[e][0][fi][l * 8];
          short8 wlo = *(const short8*)&wlds[e][1][fi][l * 8];
          cv[p] = MFMA32(ah[k0i].s, wh, cv[p]);
          cv[p] = MFMA32(ah[k0i].s, wlo, cv[p]);
          cv[p] = MFMA32(al[k0i].s, wh, cv[p]);
        }
      }
    __builtin_amdgcn_s_setprio(0);

    S4 cqh[2], cql[2], ckh[2], ckl[2], va[2];
    #pragma unroll
    for (int p = 0; p < 2; ++p) {
      cqh[p].u[0] = pk_hi(cq[p][0], cq[p][1]);
      cqh[p].u[1] = pk_hi(cq[p][2], cq[p][3]);
      cql[p].u[0] = pk_hi(cq[p][0] - btrunc(cq[p][0]), cq[p][1] - btrunc(cq[p][1]));
      cql[p].u[1] = pk_hi(cq[p][2] - btrunc(cq[p][2]), cq[p][3] - btrunc(cq[p][3]));
      ckh[p].u[0] = pk_hi(ck[p][0], ck[p][1]);
      ckh[p].u[1] = pk_hi(ck[p][2], ck[p][3]);
      ckl[p].u[0] = pk_hi(ck[p][0] - btrunc(ck[p][0]), ck[p][1] - btrunc(ck[p][1]));
      ckl[p].u[1] = pk_hi(ck[p][2] - btrunc(ck[p][2]), ck[p][3] - btrunc(ck[p][3]));
      va[p].u[0] = pk_rnd(cv[p][0], cv[p][1]);
      va[p].u[1] = pk_rnd(cv[p][2], cv[p][3]);
    }

    f32x4 eng = fz;
    #pragma unroll
    for (int p = 0; p < 2; ++p) {
      eng = MFMA16(ckh[p].s, cqh[p].s, eng);
      eng = MFMA16(ckh[p].s, cql[p].s, eng);
      eng = MFMA16(ckl[p].s, cqh[p].s, eng);
    }

    float w[4];
    {
      float mloc = -1e30f;
      if (g < 3) {
        mloc = eng[0];
        #pragma unroll
        for (int r = 1; r < 4; ++r) mloc = fmaxf(mloc, eng[r]);
      }
      float mx = mloc;
      mx = fmaxf(mx, __shfl_xor(mx, 16));
      mx = fmaxf(mx, __shfl_xor(mx, 32));
      float sloc = 0.f;
      #pragma unroll
      for (int r = 0; r < 4; ++r) {
        w[r] = (g < 3) ? __expf(eng[r] - mx) : 0.f;
        sloc += w[r];
      }
      float sm = sloc;
      sm += __shfl_xor(sm, 16);
      sm += __shfl_xor(sm, 32);
      float inv = 1.f / sm;
      #pragma unroll
      for (int r = 0; r < 4; ++r) w[r] *= inv;
    }

    S4 wh_, wl_;
    wh_.u[0] = pk_hi(w[0], w[1]);
    wh_.u[1] = pk_hi(w[2], w[3]);
    wl_.u[0] = pk_hi(w[0] - btrunc(w[0]), w[1] - btrunc(w[1]));
    wl_.u[1] = pk_hi(w[2] - btrunc(w[2]), w[3] - btrunc(w[3]));
    f32x4 hat[2];
    #pragma unroll
    for (int p = 0; p < 2; ++p) {
      hat[p] = MFMA16(va[p].s, wh_.s, fz);
      hat[p] = MFMA16(va[p].s, wl_.s, hat[p]);
    }

    float dot = 0.f, na = 0.f, nb = 0.f;
    #pragma unroll
    for (int p = 0; p < 2; ++p)
      #pragma unroll
      for (int r = 0; r < 4; ++r) {
        float a = cmem[p][r], h = hat[p][r];
        dot += a * h; na += a * a; nb += h * h;
      }
    dot += __shfl_xor(dot, 16); dot += __shfl_xor(dot, 32);
    na  += __shfl_xor(na, 16);  na  += __shfl_xor(na, 32);
    nb  += __shfl_xor(nb, 16);  nb  += __shfl_xor(nb, 32);
    if (g == 0 && c < kT) {
      float cvv = dot / fmaxf(sqrtf(na) * sqrtf(nb), 1e-8f);
      out[(size_t)site * (kT * kE) + c * kE + e] = cvv;
    }
  };

  // ---- unroll-2 site sweep; 6 tasks/group, strict hA/hB alternation ----
  float hA[16], hB[16], pA[3], pB[3];
  f32x4 cmem[2];
  int site = b * kWaves + wv;
  load_h(h0, site, hA);
  load_p(site, pA);
  for (int it = 0; it < kIters; it += 2) {
    const int s1 = site, s2 = site + kStride;
    // s1: e0(hA) e1(hB) e2(hA)
    load_h(h1, s1, hB);
    if (s1 < kSites) { memfn(pA, cmem); body(s1, 0, hA, cmem); }
    load_h(h2, s1, hA);
    if (s1 < kSites) body(s1, 1, hB, cmem);
    load_h(h0, s2, hB);
    load_p(s2, pB);
    if (s1 < kSites) body(s1, 2, hA, cmem);
    // s2: e0(hB) e1(hA) e2(hB)
    load_h(h1, s2, hA);
    if (s2 < kSites) { memfn(pB, cmem); body(s2, 0, hB, cmem); }
    load_h(h2, s2, hB);
    if (s2 < kSites) body(s2, 1, hA, cmem);
    load_h(h0, s2 + kStride, hA);
    load_p(s2 + kStride, pA);
    if (s2 < kSites) body(s2, 2, hB, cmem);
    site += 2 * kStride;
  }
}

}  // namespace

extern "C" void kernel_launch(void* const* d_in, const int* in_sizes, int n_in,
                              void* d_out, int out_size, void* d_ws, size_t ws_size,
                              hipStream_t stream) {
  const float* input = (const float*)d_in[0];
  const float* h0    = (const float*)d_in[1];
  const float* h1    = (const float*)d_in[2];
  const float* h2    = (const float*)d_in[3];
  const float* memw  = (const float*)d_in[4];
  const float* iq    = (const float*)d_in[5];
  const float* hq    = (const float*)d_in[6];
  const float* kw    = (const float*)d_in[7];
  const float* vw    = (const float*)d_in[8];
  float* out = (float*)d_out;

  testam_mfma<<<kNB, kThreads, 0, stream>>>(
      input, h0, h1, h2, memw, iq, hq, kw, vw, out);
}